// Round 13
// baseline (10473.657 us; speedup 1.0000x reference)
//
#include <hip/hip_runtime.h>
#include <stdint.h>

// 3-layer LSTM (H=64, B=256, S=4096, DIN=1) + linear head.
// R18: THREE BLOCKS PER ELEMENT (one per layer), grid 768 = 3 blocks/CU.
// R12c-R17 proved: tick = MFMA + VALU serially, because the per-tick barrier
// phase-locks all waves, and the barrier cannot go away (group self-
// recurrence is cross-wave at distance 1). Fix: per-layer 4-wave blocks.
//  - self-recurrence: raw s_barrier + lgkmcnt(0) (LDS-only; no vmcnt drain)
//    within the block's 4 waves;
//  - layer->layer h handoff: L3 ring buffers (agent-scope relaxed atomics,
//    sc-bit bypass of non-coherent L1/L2), produced-counter flags, data
//    PREFETCHED one tick ahead (~500cy L3 latency hidden under the tick);
//  - blocks share NO barrier -> 3 blocks/CU drift -> one block's MFMA
//    overlaps another's act VALU (m114), per-SIMD totals unchanged;
//  - producer throttled by consumer-progress flags (ring depth 32, checked
//    every 8 steps; steady-state margin ~20 steps -> no spin); ALL spins
//    bounded -> loud wrong-answer, never a hang.
// Carried: h=A-operand row-replicated MFMA; pinned pre-packed B-frags;
// bias in persistent MFMA C regs; head = 2 MFMAs on l2-wave0 reading own
// LDS h2; y staged 32/store.

#define SQ 4096
#define HH 64
#define NB 256
#define SPIN 2048

// ws u32 offsets
#define WOFF_FLAG0 41472   // produced-flag: h0 ring   [256]
#define WOFF_FLAG1 41728   // produced-flag: h1 ring   [256]
#define WOFF_CONS1 41984   // l1 consumer progress     [256]
#define WOFF_CONS2 42240   // l2 consumer progress     [256]
#define WOFF_RING0 65536   // h0 ring: 256 elem x 32 slots x 32 u32
#define WOFF_RING1 327680  // h1 ring: same
#define WS_U32_TOTAL 589824

typedef _Float16 h2    __attribute__((ext_vector_type(2)));
typedef _Float16 f16x8 __attribute__((ext_vector_type(8)));
typedef float    f32x4 __attribute__((ext_vector_type(4)));

__device__ __forceinline__ float frcp(float x)  { return __builtin_amdgcn_rcpf(x); }
__device__ __forceinline__ float fexp2(float x) { return __builtin_amdgcn_exp2f(x); }

__device__ __forceinline__ void pin4(uint4& r) {
    asm volatile("" : "+v"(r.x), "+v"(r.y), "+v"(r.z), "+v"(r.w));
}
__device__ __forceinline__ void pinv(f32x4& r) {
    float t0 = r[0], t1 = r[1], t2 = r[2], t3 = r[3];
    asm volatile("" : "+v"(t0), "+v"(t1), "+v"(t2), "+v"(t3));
    r[0] = t0; r[1] = t1; r[2] = t2; r[3] = t3;
}

// agent-scope (device) atomics: sc bits -> serviced at L3 (coherent point)
__device__ __forceinline__ uint32_t fldu(const uint32_t* p) {
    return __hip_atomic_load(p, __ATOMIC_RELAXED, __HIP_MEMORY_SCOPE_AGENT);
}
__device__ __forceinline__ void fstu(uint32_t* p, uint32_t v) {
    __hip_atomic_store(p, v, __ATOMIC_RELAXED, __HIP_MEMORY_SCOPE_AGENT);
}

// D = A(h, rows replicated) x B(weights) + C
__device__ __forceinline__ f32x4 mm(uint4 hv, uint4 wv, f32x4 c) {
    return __builtin_amdgcn_mfma_f32_16x16x32_f16(
        __builtin_bit_cast(f16x8, hv), __builtin_bit_cast(f16x8, wv), c, 0, 0, 0);
}

// ---- prep: weights -> MFMA B-frags (UNCHANGED layout) + zero sync flags.
__global__ __launch_bounds__(256)
void prep_weights(const float* __restrict__ Whh0, const float* __restrict__ Wih1,
                  const float* __restrict__ Whh1, const float* __restrict__ Wih2,
                  const float* __restrict__ Whh2, const float* __restrict__ Wlin,
                  uint32_t* __restrict__ ws)
{
    const int idx = blockIdx.x * 256 + threadIdx.x;   // 0..42495
    if (idx >= 41472) { ws[idx] = 0; return; }        // flags region
    if (idx >= 40960) {                               // y-fragment region
        const int r  = idx - 40960;
        const int jj = r & 3;
        const int l  = (r >> 2) & 63;
        const int kk = (r >> 8) & 1;
        const int n  = l & 15;
        const int krow = ((l >> 4) << 3) + 2 * jj;
        const int ku   = 32 * kk + krow;
        h2 t;
        t[0] = (_Float16)((n == 0) ? Wlin[ku]     : 0.f);
        t[1] = (_Float16)((n == 0) ? Wlin[ku + 1] : 0.f);
        ws[idx] = __builtin_bit_cast(uint32_t, t);
        return;
    }
    int r, ktbits;
    const float *Wi = nullptr, *Wh;
    if (idx < 8192)       { r = idx;         ktbits = 1; Wh = Whh0; }
    else if (idx < 24576) { r = idx - 8192;  ktbits = 2; Wi = Wih1; Wh = Whh1; }
    else                  { r = idx - 24576; ktbits = 2; Wi = Wih2; Wh = Whh2; }
    const int jj  = r & 3;
    const int l   = (r >> 2) & 63;
    const int rem = r >> 8;
    const int kt  = rem & ((1 << ktbits) - 1);
    const int tw  = rem >> ktbits;
    const int j   = tw & 3;
    const int w   = tw >> 2;
    const int n   = l & 15;
    const int krow = ((l >> 4) << 3) + 2 * jj;
    const int orow = 64 * j + 16 * w + n;
    int kcol = 32 * kt + krow;
    const float* M;
    if (ktbits == 1)    { M = Wh; }
    else if (kcol < 64) { M = Wi; }
    else                { M = Wh; kcol -= 64; }
    h2 t;
    t[0] = (_Float16)M[orow * HH + kcol];
    t[1] = (_Float16)M[orow * HH + kcol + 1];
    ws[idx] = __builtin_bit_cast(uint32_t, t);
}

template<int ROLE>
__device__ __forceinline__ void run_block(
    int b, int tid,
    const uint32_t* __restrict__ wpk, uint32_t* __restrict__ wsu,
    const float* __restrict__ Wih0,
    const float* __restrict__ bi, const float* __restrict__ bh,
    const float* __restrict__ blin,
    float* __restrict__ out,
    float* xrow, uint4 (*hbf)[8], float* ystage)
{
    const int w    = tid >> 6;
    const int l    = tid & 63;
    const int n    = l & 15;
    const int q    = l >> 4;
    const int unit = 16 * w + n;
    constexpr int KT = (ROLE == 0) ? 2 : 4;
    constexpr int GB = (ROLE == 0) ? 0 : (ROLE == 1) ? 8192 : 24576;

    // ---- weights ----
    auto fr = [&](int j_, int kt_) {
        return *reinterpret_cast<const uint4*>(
            wpk + GB + (((w * 4 + j_) * KT + kt_) * 64 + l) * 4);
    };
    uint4 w00 = fr(0, 0), w01 = fr(0, 1), w10 = fr(1, 0), w11 = fr(1, 1),
          w20 = fr(2, 0), w21 = fr(2, 1), w30 = fr(3, 0), w31 = fr(3, 1);
    pin4(w00); pin4(w01); pin4(w10); pin4(w11);
    pin4(w20); pin4(w21); pin4(w30); pin4(w31);
    uint4 w02 = {}, w03 = {}, w12 = {}, w13 = {},
          w22 = {}, w23 = {}, w32 = {}, w33 = {};
    if constexpr (ROLE != 0) {
        w02 = fr(0, 2); w03 = fr(0, 3); w12 = fr(1, 2); w13 = fr(1, 3);
        w22 = fr(2, 2); w23 = fr(2, 3); w32 = fr(3, 2); w33 = fr(3, 3);
        pin4(w02); pin4(w03); pin4(w12); pin4(w13);
        pin4(w22); pin4(w23); pin4(w32); pin4(w33);
    }
    uint4 wy2 = {}, wy3 = {};
    f32x4 cy = {0.f, 0.f, 0.f, 0.f};
    if constexpr (ROLE == 2) {
        if (w == 0) {
            wy2 = *reinterpret_cast<const uint4*>(wpk + 40960 + (0 * 64 + l) * 4);
            wy3 = *reinterpret_cast<const uint4*>(wpk + 40960 + (1 * 64 + l) * 4);
            pin4(wy2); pin4(wy3);
            const float bv = blin[0];
            cy = f32x4{bv, bv, bv, bv};
            pinv(cy);
        }
    }

    // ---- bias in persistent C regs ----
    const float bs0 = bi[unit]       + bh[unit];
    const float bs1 = bi[64 + unit]  + bh[64 + unit];
    const float bs2 = bi[128 + unit] + bh[128 + unit];
    const float bs3 = bi[192 + unit] + bh[192 + unit];
    f32x4 cb0 = {bs0, bs0, bs0, bs0};  pinv(cb0);
    f32x4 cb1 = {bs1, bs1, bs1, bs1};  pinv(cb1);
    f32x4 cb2 = {bs2, bs2, bs2, bs2};  pinv(cb2);
    f32x4 cb3 = {bs3, bs3, bs3, bs3};  pinv(cb3);

    float wx0 = 0.f, wx1 = 0.f, wx2 = 0.f, wx3 = 0.f;
    if constexpr (ROLE == 0) {
        wx0 = Wih0[unit];       wx1 = Wih0[64 + unit];
        wx2 = Wih0[128 + unit]; wx3 = Wih0[192 + unit];
    }

    // ---- sync plumbing ----
    uint32_t* Fprod = wsu + ((ROLE == 0) ? WOFF_FLAG0 : WOFF_FLAG1) + b;
    uint32_t* Fin   = wsu + ((ROLE == 1) ? WOFF_FLAG0 : WOFF_FLAG1) + b;
    uint32_t* Cin   = wsu + ((ROLE == 0) ? WOFF_CONS1 : WOFF_CONS2) + b;
    uint32_t* Cself = wsu + ((ROLE == 1) ? WOFF_CONS1 : WOFF_CONS2) + b;
    uint32_t* ringP = wsu + ((ROLE == 0) ? WOFF_RING0 : WOFF_RING1) + b * 1024;
    uint32_t* ringI = wsu + ((ROLE == 1) ? WOFF_RING0 : WOFF_RING1) + b * 1024;

    uint4 ha0 = {}, ha1 = {};
    uint32_t flagv = 0;
    int have = -1;
    float cc = 0.f;

    for (int s = 0; s < SQ; ++s) {
        const int rd = s & 1, wr = rd ^ 1;

        // ---- producer duties (wave 0 of l0/l1) ----
        if constexpr (ROLE != 2) {
            if (w == 0) {
                if ((s & 7) == 0 && s >= 32) {
                    const uint32_t need = (uint32_t)(s - 25);   // ring-32 WAR
                    for (int it = 0; it < SPIN; ++it)
                        if (fldu(Cin) >= need) break;
                }
                // drain last tick's data store (old -> ~free), then flag
                asm volatile("s_waitcnt vmcnt(0)" ::: "memory");
                if (l == 0 && s >= 2) fstu(Fprod, (uint32_t)(s - 1));
                if (s >= 1 && l < 32) {
                    const uint32_t hw = ((const uint32_t*)&hbf[rd])[l];
                    fstu(ringP + ((s - 1) & 31) * 32 + l, hw);
                }
            }
        }

        // ---- consumer: ensure h_in(s) in regs (slow path = startup only) --
        if constexpr (ROLE != 0) {
            if (have < s) {
                for (int it = 0; it < SPIN; ++it) {
                    flagv = fldu(Fin);
                    if (flagv >= (uint32_t)(s + 1)) break;
                }
                const uint32_t* bse = ringI + (s & 31) * 32;
                ha0 = uint4{fldu(bse + q * 4),     fldu(bse + q * 4 + 1),
                            fldu(bse + q * 4 + 2), fldu(bse + q * 4 + 3)};
                ha1 = uint4{fldu(bse + 16 + q * 4),     fldu(bse + 16 + q * 4 + 1),
                            fldu(bse + 16 + q * 4 + 2), fldu(bse + 16 + q * 4 + 3)};
                have = s;
            }
        }

        // ---- MFMA matvec ----
        const uint4 c0 = hbf[rd][q], c1 = hbf[rd][4 + q];   // own h(s-1)
        f32x4 d0, d1, d2, d3;
        if constexpr (ROLE == 0) {
            d0 = mm(c0, w00, cb0);  d1 = mm(c0, w10, cb1);
            d2 = mm(c0, w20, cb2);  d3 = mm(c0, w30, cb3);
            d0 = mm(c1, w01, d0);   d1 = mm(c1, w11, d1);
            d2 = mm(c1, w21, d2);   d3 = mm(c1, w31, d3);
        } else {
            d0 = mm(ha0, w00, cb0); d1 = mm(ha0, w10, cb1);
            d2 = mm(ha0, w20, cb2); d3 = mm(ha0, w30, cb3);
            d0 = mm(ha1, w01, d0);  d1 = mm(ha1, w11, d1);
            d2 = mm(ha1, w21, d2);  d3 = mm(ha1, w31, d3);
            d0 = mm(c0, w02, d0);   d1 = mm(c0, w12, d1);
            d2 = mm(c0, w22, d2);   d3 = mm(c0, w32, d3);
            d0 = mm(c1, w03, d0);   d1 = mm(c1, w13, d1);
            d2 = mm(c1, w23, d2);   d3 = mm(c1, w33, d3);
        }

        // ---- head (l2 wave0): y(s-1) from own published h2 ----
        if constexpr (ROLE == 2) {
            if (w == 0) {
                const int sy = s - 1;
                if (sy >= 0) {
                    f32x4 d4 = mm(c0, wy2, cy);
                    d4 = mm(c1, wy3, d4);
                    if (l == 0) ystage[sy & 31] = d4[0];
                    if ((sy & 31) == 31) {
                        const float yv = ystage[l & 31];
                        if (l < 32) out[b * SQ + (sy - 31) + l] = yv;
                    }
                }
            }
        }

        // ---- consumer: prefetch h_in(s+1); refresh flag for next tick ----
        if constexpr (ROLE != 0) {
            const uint32_t fnew = fldu(Fin);
            if (flagv >= (uint32_t)(s + 2) && have == s && s + 1 < SQ) {
                const uint32_t* bse = ringI + ((s + 1) & 31) * 32;
                ha0 = uint4{fldu(bse + q * 4),     fldu(bse + q * 4 + 1),
                            fldu(bse + q * 4 + 2), fldu(bse + q * 4 + 3)};
                ha1 = uint4{fldu(bse + 16 + q * 4),     fldu(bse + 16 + q * 4 + 1),
                            fldu(bse + 16 + q * 4 + 2), fldu(bse + 16 + q * 4 + 3)};
                have = s + 1;
            }
            if (fnew > flagv) flagv = fnew;
            if ((s & 7) == 7 && tid == 0) fstu(Cself, (uint32_t)(s + 1));
        }

        // ---- activation (all lanes redundant; D rows replicated) ----
        float gi = d0[0], gf = d1[0], gg = d2[0], go = d3[0];
        if constexpr (ROLE == 0) {
            const float xT = xrow[s];
            gi += wx0 * xT; gf += wx1 * xT;
            gg += wx2 * xT; go += wx3 * xT;
        }
        const float i_ = frcp(1.f + fexp2(gi * -1.44269504f));
        const float f_ = frcp(1.f + fexp2(gf * -1.44269504f));
        const float o_ = frcp(1.f + fexp2(go * -1.44269504f));
        const float tg = 2.f * frcp(1.f + fexp2(gg * -2.88539008f)) - 1.f;
        cc = f_ * cc + i_ * tg;
        const float tc = fminf(fmaxf(cc, -15.f), 15.f);
        const float e  = fexp2(tc * -2.88539008f);
        const float h  = o_ * ((1.f - e) * frcp(1.f + e));
        if (l < 16) {
            ((_Float16*)&hbf[wr])[unit] = (_Float16)h;
            if (s == SQ - 1) {
                out[NB * SQ + ROLE * NB * HH + b * HH + unit] = h;
                out[NB * SQ + 3 * NB * HH + ROLE * NB * HH + b * HH + unit] = cc;
            }
        }

        // ---- LDS-only barrier: no vmcnt drain (keeps L3 ops in flight) ----
        asm volatile("s_waitcnt lgkmcnt(0)" ::: "memory");
        __builtin_amdgcn_s_barrier();
        asm volatile("" ::: "memory");
    }

    // ---- tails ----
    if constexpr (ROLE != 2) {
        if (w == 0) {              // publish final h(SQ-1)
            if (l < 32) {
                const uint32_t hw = ((const uint32_t*)&hbf[SQ & 1])[l];
                fstu(ringP + ((SQ - 1) & 31) * 32 + l, hw);
            }
            asm volatile("s_waitcnt vmcnt(0)" ::: "memory");
            if (l == 0) fstu(Fprod, (uint32_t)SQ);
        }
    }
    if constexpr (ROLE == 2) {
        if (w == 0) {              // final head tick: y(SQ-1)
            const uint4 t0 = hbf[SQ & 1][q], t1 = hbf[SQ & 1][4 + q];
            f32x4 d4 = mm(t0, wy2, cy);
            d4 = mm(t1, wy3, d4);
            if (l == 0) ystage[31] = d4[0];
            const float yv = ystage[l & 31];
            if (l < 32) out[b * SQ + (SQ - 32) + l] = yv;
        }
    }
}

__global__ __launch_bounds__(256)
__attribute__((amdgpu_waves_per_eu(3)))
void lstm3_fused(
    const float* __restrict__ x,
    const float* __restrict__ Wih0,
    const float* __restrict__ bih0, const float* __restrict__ bhh0,
    const float* __restrict__ bih1, const float* __restrict__ bhh1,
    const float* __restrict__ bih2, const float* __restrict__ bhh2,
    const float* __restrict__ blin,
    const uint32_t* __restrict__ wpk, uint32_t* __restrict__ wsu,
    float* __restrict__ out)
{
    const int role = blockIdx.x >> 8;      // 0,1,2 = layer
    const int b    = blockIdx.x & 255;     // batch element
    const int tid  = threadIdx.x;

    __shared__ __align__(16) float xrow[SQ];
    __shared__ __align__(16) uint4 hbf[2][8];      // own-layer h, 2 buffers
    __shared__ __align__(16) float ystage[32];

    if (role == 0)
        for (int i = tid; i < SQ; i += 256) xrow[i] = x[b * SQ + i];
    if (tid < 16) ((uint4*)hbf)[tid] = make_uint4(0, 0, 0, 0);
    __syncthreads();

    if (role == 0)
        run_block<0>(b, tid, wpk, wsu, Wih0, bih0, bhh0, blin, out, xrow, hbf, ystage);
    else if (role == 1)
        run_block<1>(b, tid, wpk, wsu, Wih0, bih1, bhh1, blin, out, xrow, hbf, ystage);
    else
        run_block<2>(b, tid, wpk, wsu, Wih0, bih2, bhh2, blin, out, xrow, hbf, ystage);
}

extern "C" void kernel_launch(void* const* d_in, const int* in_sizes, int n_in,
                              void* d_out, int out_size, void* d_ws, size_t ws_size,
                              hipStream_t stream) {
    const float* x    = (const float*)d_in[0];
    const float* Wih0 = (const float*)d_in[1];
    const float* Whh0 = (const float*)d_in[2];
    const float* bih0 = (const float*)d_in[3];
    const float* bhh0 = (const float*)d_in[4];
    const float* Wih1 = (const float*)d_in[5];
    const float* Whh1 = (const float*)d_in[6];
    const float* bih1 = (const float*)d_in[7];
    const float* bhh1 = (const float*)d_in[8];
    const float* Wih2 = (const float*)d_in[9];
    const float* Whh2 = (const float*)d_in[10];
    const float* bih2 = (const float*)d_in[11];
    const float* bhh2 = (const float*)d_in[12];
    const float* Wlin = (const float*)d_in[13];
    const float* blin = (const float*)d_in[14];
    float* out = (float*)d_out;

    uint32_t* wpk = (uint32_t*)d_ws;   // needs WS_U32_TOTAL*4 = 2.25 MiB
    prep_weights<<<166, 256, 0, stream>>>(Whh0, Wih1, Whh1, Wih2, Whh2, Wlin, wpk);
    lstm3_fused<<<768, 256, 0, stream>>>(x, Wih0, bih0, bhh0,
                                         bih1, bhh1, bih2, bhh2,
                                         blin, wpk, wpk, out);
}

// Round 14
// 2883.101 us; speedup vs baseline: 3.6328x; 3.6328x over previous
//
#include <hip/hip_runtime.h>
#include <stdint.h>

// 3-layer LSTM (H=64, B=256, S=4096, DIN=1) + linear head.
// One block/batch element; 768 thr = 12 waves = 3 groups x 4 (group=layer),
// skew 1 tick/layer (l0@T: step T, l1: T-1, l2: T-2, head y: T-3).
// R19 = R12c (2580us champion) + ROTATING 3-LEVEL s_setprio.
// Model (R12c-R17 counters): tick = 1510cy = MFMA drain (48/SIMD ~786cy) +
// serialized act (~810cy VALU) because round-robin issue interleaves all
// waves' MFMAs in the pipe -> every wave's LAST MFMA completes at full
// drain -> all acts start together and serialize. R16 (prefetch) and R17
// (sched_group_barrier) were null: both act WITHIN a wave; the problem is
// CROSS-WAVE pipe ordering. The only lever for that is wave priority:
// each tick, wave with (grp-T)%3==0 raises prio2, next prio1, last prio0,
// during ds_read+MFMA issue only (reset before act). First wave's MFMAs
// drain ~260cy -> its act overlaps the others' MFMAs; expected tick
// ~1050-1300. Rotation equalizes recurrence slack (1-tick skew buffer).
// T5 mechanism with manufactured role-split (m218b: +21-25% when roles
// differ; m190: 0% when symmetric).
// Carried from R12c: h=A-operand row-replicated MFMA (every lane holds all
// 4 gates of unit 16w+(l&15)); pinned pre-packed B-frags; bias in
// persistent MFMA C regs; head 2 MFMAs on l0w1; y staged 32/store.

#define SQ 4096
#define HH 64
#define NB 256

typedef _Float16 h2    __attribute__((ext_vector_type(2)));
typedef _Float16 f16x8 __attribute__((ext_vector_type(8)));
typedef float    f32x4 __attribute__((ext_vector_type(4)));

__device__ __forceinline__ float frcp(float x)  { return __builtin_amdgcn_rcpf(x); }
__device__ __forceinline__ float fexp2(float x) { return __builtin_amdgcn_exp2f(x); }

__device__ __forceinline__ void pin4(uint4& r) {
    asm volatile("" : "+v"(r.x), "+v"(r.y), "+v"(r.z), "+v"(r.w));
}
__device__ __forceinline__ void pinv(f32x4& r) {
    float t0 = r[0], t1 = r[1], t2 = r[2], t3 = r[3];
    asm volatile("" : "+v"(t0), "+v"(t1), "+v"(t2), "+v"(t3));
    r[0] = t0; r[1] = t1; r[2] = t2; r[3] = t3;
}

// D = A(h, rows replicated) x B(weights) + C
__device__ __forceinline__ f32x4 mm(uint4 hv, uint4 wv, f32x4 c) {
    return __builtin_amdgcn_mfma_f32_16x16x32_f16(
        __builtin_bit_cast(f16x8, hv), __builtin_bit_cast(f16x8, wv), c, 0, 0, 0);
}

// ---- prep: fp32 weights -> MFMA B-fragments (packed fp16 pairs). UNCHANGED.
// Regions: grp0 [0,8192) u32 (Whh0, KT=2); grp1 [8192,24576) ([Wih1|Whh1],
// KT=4); grp2 [24576,40960) ([Wih2|Whh2], KT=4); y-frag [40960,41472):
// 2 K-tiles (h2 range), col0 = Wlin, cols 1-15 = 0.
__global__ __launch_bounds__(256)
void prep_weights(const float* __restrict__ Whh0, const float* __restrict__ Wih1,
                  const float* __restrict__ Whh1, const float* __restrict__ Wih2,
                  const float* __restrict__ Whh2, const float* __restrict__ Wlin,
                  uint32_t* __restrict__ ws)
{
    const int idx = blockIdx.x * 256 + threadIdx.x;   // 0..41471
    if (idx >= 40960) {                               // y-fragment region
        const int r  = idx - 40960;
        const int jj = r & 3;
        const int l  = (r >> 2) & 63;
        const int kk = (r >> 8) & 1;                  // 0 -> kt2, 1 -> kt3
        const int n  = l & 15;
        const int krow = ((l >> 4) << 3) + 2 * jj;
        const int ku   = 32 * kk + krow;              // h2 unit index
        h2 t;
        t[0] = (_Float16)((n == 0) ? Wlin[ku]     : 0.f);
        t[1] = (_Float16)((n == 0) ? Wlin[ku + 1] : 0.f);
        ws[idx] = __builtin_bit_cast(uint32_t, t);
        return;
    }
    int r, ktbits;
    const float *Wi = nullptr, *Wh;
    if (idx < 8192)       { r = idx;         ktbits = 1; Wh = Whh0; }
    else if (idx < 24576) { r = idx - 8192;  ktbits = 2; Wi = Wih1; Wh = Whh1; }
    else                  { r = idx - 24576; ktbits = 2; Wi = Wih2; Wh = Whh2; }
    const int jj  = r & 3;
    const int l   = (r >> 2) & 63;
    const int rem = r >> 8;
    const int kt  = rem & ((1 << ktbits) - 1);
    const int tw  = rem >> ktbits;
    const int j   = tw & 3;
    const int w   = tw >> 2;
    const int n   = l & 15;
    const int krow = ((l >> 4) << 3) + 2 * jj;
    const int orow = 64 * j + 16 * w + n;
    int kcol = 32 * kt + krow;
    const float* M;
    if (ktbits == 1)    { M = Wh; }
    else if (kcol < 64) { M = Wi; }
    else                { M = Wh; kcol -= 64; }
    h2 t;
    t[0] = (_Float16)M[orow * HH + kcol];
    t[1] = (_Float16)M[orow * HH + kcol + 1];
    ws[idx] = __builtin_bit_cast(uint32_t, t);
}

__global__ __launch_bounds__(768)
__attribute__((amdgpu_waves_per_eu(1, 3)))
void lstm3_fused(
    const float* __restrict__ x,
    const float* __restrict__ Wih0,
    const float* __restrict__ bih0, const float* __restrict__ bhh0,
    const float* __restrict__ bih1, const float* __restrict__ bhh1,
    const float* __restrict__ bih2, const float* __restrict__ bhh2,
    const float* __restrict__ blin,
    const uint32_t* __restrict__ wpk,
    float* __restrict__ out)
{
    const int b    = blockIdx.x;
    const int tid  = threadIdx.x;
    const int grp  = tid >> 8;         // layer 0,1,2
    const int k    = tid & 255;
    const int w    = k >> 6;           // wave within group
    const int l    = k & 63;           // lane
    const int n    = l & 15;
    const int q    = l >> 4;           // 16-lane sub-group (A k-slice)
    const int unit = 16 * w + n;       // this lane's hidden unit
    const bool grp0w1 = (grp == 0) && (w == 1);   // head wave

    __shared__ __align__(16) float xrow[SQ + 4];
    __shared__ __align__(16) uint4 hbf[2][3][8];   // [buf][layer][64 fp16]
    __shared__ __align__(16) float ystage[32];     // head staging (1 wave)

    for (int i = tid; i < SQ; i += 768) xrow[i] = x[b * SQ + i];
    if (tid < 4) xrow[SQ + tid] = 0.f;
    if (tid < 48) ((uint4*)hbf)[tid] = make_uint4(0, 0, 0, 0);

    // ---- weights: MFMA B-fragments from workspace ----
    const int gbase = (grp == 0) ? 0 : (grp == 1) ? 8192 : 24576;
    const int KT    = (grp == 0) ? 2 : 4;
    const uint32_t* wbp = wpk + gbase;
    auto fr = [&](int j_, int kt_) {
        return *reinterpret_cast<const uint4*>(
            wbp + (((w * 4 + j_) * KT + kt_) * 64 + l) * 4);
    };
    uint4 w00 = fr(0, 0), w01 = fr(0, 1), w10 = fr(1, 0), w11 = fr(1, 1),
          w20 = fr(2, 0), w21 = fr(2, 1), w30 = fr(3, 0), w31 = fr(3, 1);
    pin4(w00); pin4(w01); pin4(w10); pin4(w11);
    pin4(w20); pin4(w21); pin4(w30); pin4(w31);
    uint4 w02 = {}, w03 = {}, w12 = {}, w13 = {},
          w22 = {}, w23 = {}, w32 = {}, w33 = {};
    if (grp != 0) {
        w02 = fr(0, 2); w03 = fr(0, 3); w12 = fr(1, 2); w13 = fr(1, 3);
        w22 = fr(2, 2); w23 = fr(2, 3); w32 = fr(3, 2); w33 = fr(3, 3);
        pin4(w02); pin4(w03); pin4(w12); pin4(w13);
        pin4(w22); pin4(w23); pin4(w32); pin4(w33);
    }
    // head fragments (grp0w1 only)
    uint4 wy2 = {}, wy3 = {};
    f32x4 cy = {0.f, 0.f, 0.f, 0.f};
    if (grp0w1) {
        wy2 = *reinterpret_cast<const uint4*>(wpk + 40960 + (0 * 64 + l) * 4);
        wy3 = *reinterpret_cast<const uint4*>(wpk + 40960 + (1 * 64 + l) * 4);
        pin4(wy2); pin4(wy3);
        const float bv = blin[0];
        cy = f32x4{bv, bv, bv, bv};
        pinv(cy);
    }

    // ---- persistent bias C-operands (gate j of unit -> row 64j + unit) ----
    const float* bi = (grp == 0) ? bih0 : (grp == 1) ? bih1 : bih2;
    const float* bh = (grp == 0) ? bhh0 : (grp == 1) ? bhh1 : bhh2;
    const float bs0 = bi[unit]       + bh[unit];
    const float bs1 = bi[64 + unit]  + bh[64 + unit];
    const float bs2 = bi[128 + unit] + bh[128 + unit];
    const float bs3 = bi[192 + unit] + bh[192 + unit];
    f32x4 cb0 = {bs0, bs0, bs0, bs0};  pinv(cb0);
    f32x4 cb1 = {bs1, bs1, bs1, bs1};  pinv(cb1);
    f32x4 cb2 = {bs2, bs2, bs2, bs2};  pinv(cb2);
    f32x4 cb3 = {bs3, bs3, bs3, bs3};  pinv(cb3);

    float wx0 = 0.f, wx1 = 0.f, wx2 = 0.f, wx3 = 0.f;
    if (grp == 0) {
        wx0 = Wih0[unit];       wx1 = Wih0[64 + unit];
        wx2 = Wih0[128 + unit]; wx3 = Wih0[192 + unit];
    }

    const int la = (grp == 2) ? 1 : 0;     // Wih-side h source layer
    const int lb = grp;                    // Whh-side h source layer (own)
    const uint4* pA[2] = { &hbf[0][la][q], &hbf[1][la][q] };
    const uint4* pB[2] = { &hbf[0][lb][q], &hbf[1][lb][q] };
    const uint4* pY[2] = { &hbf[0][2][q],  &hbf[1][2][q] };   // head source
    _Float16* pH[2] = { (_Float16*)&hbf[0][grp][0] + unit,
                        (_Float16*)&hbf[1][grp][0] + unit };

    float cc = 0.f;                        // cell state (replicated all lanes)

    __syncthreads();

    auto tick = [&](int T, int rd, int tp) {
        const int wr = rd ^ 1;

        // ---- rotating cross-wave pipe priority: wave with rank 0 this
        // tick issues its ds_reads + MFMAs first, rank 1 second. Raised
        // only through the MFMA cluster, reset before act. grp is the
        // per-SIMD wave slot (wid>>2), so ranks rotate across SIMD peers.
        int rr = grp - tp; if (rr < 0) rr += 3;
        if (rr == 0)      __builtin_amdgcn_s_setprio(2);
        else if (rr == 1) __builtin_amdgcn_s_setprio(1);

        float xT = 0.f;
        if (grp == 0) xT = xrow[T];        // padded; broadcast read

        // ---- MFMA matvec: D[., c] = sum_k hcat[k] * Wpk[k, c] + bias ----
        const uint4 a0 = pA[rd][0], a1 = pA[rd][4];
        f32x4 d0 = mm(a0, w00, cb0);
        f32x4 d1 = mm(a0, w10, cb1);
        f32x4 d2 = mm(a0, w20, cb2);
        f32x4 d3 = mm(a0, w30, cb3);
        d0 = mm(a1, w01, d0);  d1 = mm(a1, w11, d1);
        d2 = mm(a1, w21, d2);  d3 = mm(a1, w31, d3);
        if (grp != 0) {
            const uint4 c0 = pB[rd][0], c1 = pB[rd][4];
            d0 = mm(c0, w02, d0);  d1 = mm(c0, w12, d1);
            d2 = mm(c0, w22, d2);  d3 = mm(c0, w32, d3);
            d0 = mm(c1, w03, d0);  d1 = mm(c1, w13, d1);
            d2 = mm(c1, w23, d2);  d3 = mm(c1, w33, d3);
        }
        __builtin_amdgcn_s_setprio(0);     // pipe order set; act at base prio

        if (grp0w1) {
            // head: y_{T-3} = Wlin . h2_{T-3} + blin; h2_{T-3} is in the
            // PUBLISHED buffer hbf[rd][2] (this tick writes only rd^1).
            const int sy = T - 3;
            if (sy >= 0 && sy < SQ) {
                const uint4 y0 = pY[rd][0], y1 = pY[rd][4];
                f32x4 d4 = mm(y0, wy2, cy);
                d4 = mm(y1, wy3, d4);
                if (l == 0) ystage[sy & 31] = d4[0];   // ds_write, lgkm-only
                if ((sy & 31) == 31) {
                    const float yv = ystage[l & 31];
                    if (l < 32) out[b * SQ + (sy - 31) + l] = yv;
                }
            }
        }

        const int step = T - grp;
        if (step >= 0 && step < SQ) {      // wave-uniform guard
            // all 64 lanes redundantly process unit 16w+n (D rows replicated)
            float gi = d0[0], gf = d1[0], gg = d2[0], go = d3[0];
            if (grp == 0) {
                gi += wx0 * xT; gf += wx1 * xT;
                gg += wx2 * xT; go += wx3 * xT;
            }
            const float i_ = frcp(1.f + fexp2(gi * -1.44269504f));
            const float f_ = frcp(1.f + fexp2(gf * -1.44269504f));
            const float o_ = frcp(1.f + fexp2(go * -1.44269504f));
            const float tg = 2.f * frcp(1.f + fexp2(gg * -2.88539008f)) - 1.f;
            cc = f_ * cc + i_ * tg;
            const float tc = fminf(fmaxf(cc, -15.f), 15.f);
            const float e  = fexp2(tc * -2.88539008f);
            const float h  = o_ * ((1.f - e) * frcp(1.f + e));
            if (l < 16) {
                pH[wr][0] = (_Float16)h;
                if (step == SQ - 1) {
                    out[NB * SQ + grp * NB * HH + b * HH + unit] = h;
                    out[NB * SQ + 3 * NB * HH + grp * NB * HH + b * HH + unit] = cc;
                }
            }
        }
        __syncthreads();
    };

    for (int T = 0; T < SQ + 4; T += 2) {  // ticks 0..4099 (needs 0..4098)
        tick(T, 0, T % 3);
        tick(T + 1, 1, (T + 1) % 3);
    }
}

extern "C" void kernel_launch(void* const* d_in, const int* in_sizes, int n_in,
                              void* d_out, int out_size, void* d_ws, size_t ws_size,
                              hipStream_t stream) {
    const float* x    = (const float*)d_in[0];
    const float* Wih0 = (const float*)d_in[1];
    const float* Whh0 = (const float*)d_in[2];
    const float* bih0 = (const float*)d_in[3];
    const float* bhh0 = (const float*)d_in[4];
    const float* Wih1 = (const float*)d_in[5];
    const float* Whh1 = (const float*)d_in[6];
    const float* bih1 = (const float*)d_in[7];
    const float* bhh1 = (const float*)d_in[8];
    const float* Wih2 = (const float*)d_in[9];
    const float* Whh2 = (const float*)d_in[10];
    const float* bih2 = (const float*)d_in[11];
    const float* bhh2 = (const float*)d_in[12];
    const float* Wlin = (const float*)d_in[13];
    const float* blin = (const float*)d_in[14];
    float* out = (float*)d_out;

    uint32_t* wpk = (uint32_t*)d_ws;   // 41472 u32 = 162 KiB < ws_size
    prep_weights<<<162, 256, 0, stream>>>(Whh0, Wih1, Whh1, Wih2, Whh2, Wlin, wpk);
    lstm3_fused<<<NB, 768, 0, stream>>>(x, Wih0, bih0, bhh0,
                                        bih1, bhh1, bih2, bhh2,
                                        blin, wpk, out);
}

// Round 15
// 2325.122 us; speedup vs baseline: 4.5046x; 1.2400x over previous
//
#include <hip/hip_runtime.h>
#include <stdint.h>

// 3-layer LSTM (H=64, B=256, S=4096, DIN=1) + linear head.
// One block/batch element; 768 thr = 12 waves = 3 groups x 4 (group=layer).
// R20 = R12c + TIMESTEP-BATCHED INPUT-SIDE MATVECS.
// Model: tick = MFMA pipe (~40/SIMD x 19.4cy = 786) + act/sync (~720); six
// rounds proved the overlap can't be scheduled away. So cut the pipe term:
// the MFMA A operand wastes 15/16 rows on replicated h. The input-side
// contribution Wih.h_in(s) is INDEPENDENT across s -> with deeper skew
// (l0@T, l1@T-18, l2@T-36, head y@T-38), 16 steps of h_in are already
// published, and ONE 8-MFMA batch per 16 ticks computes 16 steps of
// input-gates with A-rows = 16 TIMESTEPS (D rows = steps). Results spill
// to a per-wave LDS buffer (intra-wave only); act reads 4xb32 per tick.
// Per-wave MFMA/tick: l1/l2 16 -> 8+0.5; per-SIMD ~40 -> ~25 (786->490cy).
// h lives in depth-32 LDS rings (padded 72 f16/row: 16B-aligned slices,
// 2-way banks); all reader/writer row distances verified distinct mod 32
// (lags 2..18). Weights/prep/act/barrier unchanged from R12c.
// Carried: h=A-operand MFMA; pinned pre-packed B-frags; bias in persistent
// MFMA C regs (input-batch C=0 -> no double count); head 2 MFMAs on l0w1
// reading the h2 ring at lag 38; y staged 32/store.

#define SQ 4096
#define HH 64
#define NB 256
#define SK1 18
#define SK2 36
#define SKH 38

typedef _Float16 h2    __attribute__((ext_vector_type(2)));
typedef _Float16 f16x8 __attribute__((ext_vector_type(8)));
typedef float    f32x4 __attribute__((ext_vector_type(4)));

__device__ __forceinline__ float frcp(float x)  { return __builtin_amdgcn_rcpf(x); }
__device__ __forceinline__ float fexp2(float x) { return __builtin_amdgcn_exp2f(x); }

__device__ __forceinline__ void pin4(uint4& r) {
    asm volatile("" : "+v"(r.x), "+v"(r.y), "+v"(r.z), "+v"(r.w));
}
__device__ __forceinline__ void pinv(f32x4& r) {
    float t0 = r[0], t1 = r[1], t2 = r[2], t3 = r[3];
    asm volatile("" : "+v"(t0), "+v"(t1), "+v"(t2), "+v"(t3));
    r[0] = t0; r[1] = t1; r[2] = t2; r[3] = t3;
}

// D = A x B + C (A rows = replicated h, or batched timesteps)
__device__ __forceinline__ f32x4 mm(uint4 hv, uint4 wv, f32x4 c) {
    return __builtin_amdgcn_mfma_f32_16x16x32_f16(
        __builtin_bit_cast(f16x8, hv), __builtin_bit_cast(f16x8, wv), c, 0, 0, 0);
}

// ---- prep: fp32 weights -> MFMA B-fragments (packed fp16 pairs). UNCHANGED.
// Regions: grp0 [0,8192) u32 (Whh0, KT=2); grp1 [8192,24576) ([Wih1|Whh1],
// KT=4: kt0/1=Wih, kt2/3=Whh); grp2 [24576,40960) ([Wih2|Whh2], KT=4);
// y-frag [40960,41472): 2 K-tiles, col0 = Wlin, cols 1-15 = 0.
__global__ __launch_bounds__(256)
void prep_weights(const float* __restrict__ Whh0, const float* __restrict__ Wih1,
                  const float* __restrict__ Whh1, const float* __restrict__ Wih2,
                  const float* __restrict__ Whh2, const float* __restrict__ Wlin,
                  uint32_t* __restrict__ ws)
{
    const int idx = blockIdx.x * 256 + threadIdx.x;   // 0..41471
    if (idx >= 40960) {                               // y-fragment region
        const int r  = idx - 40960;
        const int jj = r & 3;
        const int l  = (r >> 2) & 63;
        const int kk = (r >> 8) & 1;                  // 0 -> kt2, 1 -> kt3
        const int n  = l & 15;
        const int krow = ((l >> 4) << 3) + 2 * jj;
        const int ku   = 32 * kk + krow;              // h2 unit index
        h2 t;
        t[0] = (_Float16)((n == 0) ? Wlin[ku]     : 0.f);
        t[1] = (_Float16)((n == 0) ? Wlin[ku + 1] : 0.f);
        ws[idx] = __builtin_bit_cast(uint32_t, t);
        return;
    }
    int r, ktbits;
    const float *Wi = nullptr, *Wh;
    if (idx < 8192)       { r = idx;         ktbits = 1; Wh = Whh0; }
    else if (idx < 24576) { r = idx - 8192;  ktbits = 2; Wi = Wih1; Wh = Whh1; }
    else                  { r = idx - 24576; ktbits = 2; Wi = Wih2; Wh = Whh2; }
    const int jj  = r & 3;
    const int l   = (r >> 2) & 63;
    const int rem = r >> 8;
    const int kt  = rem & ((1 << ktbits) - 1);
    const int tw  = rem >> ktbits;
    const int j   = tw & 3;
    const int w   = tw >> 2;
    const int n   = l & 15;
    const int krow = ((l >> 4) << 3) + 2 * jj;
    const int orow = 64 * j + 16 * w + n;
    int kcol = 32 * kt + krow;
    const float* M;
    if (ktbits == 1)    { M = Wh; }
    else if (kcol < 64) { M = Wi; }
    else                { M = Wh; kcol -= 64; }
    h2 t;
    t[0] = (_Float16)M[orow * HH + kcol];
    t[1] = (_Float16)M[orow * HH + kcol + 1];
    ws[idx] = __builtin_bit_cast(uint32_t, t);
}

__global__ __launch_bounds__(768)
__attribute__((amdgpu_waves_per_eu(1, 3)))
void lstm3_fused(
    const float* __restrict__ x,
    const float* __restrict__ Wih0,
    const float* __restrict__ bih0, const float* __restrict__ bhh0,
    const float* __restrict__ bih1, const float* __restrict__ bhh1,
    const float* __restrict__ bih2, const float* __restrict__ bhh2,
    const float* __restrict__ blin,
    const uint32_t* __restrict__ wpk,
    float* __restrict__ out)
{
    const int b    = blockIdx.x;
    const int tid  = threadIdx.x;
    const int grp  = tid >> 8;         // layer 0,1,2
    const int k    = tid & 255;
    const int w    = k >> 6;           // wave within group
    const int l    = k & 63;           // lane
    const int n    = l & 15;
    const int q    = l >> 4;           // 16-lane sub-group (A k-slice)
    const int unit = 16 * w + n;       // this lane's hidden unit
    const bool grp0w1 = (grp == 0) && (w == 1);   // head wave
    const int wg   = (tid >> 6) - 4;   // gin region (grp1/2 only: 0..7)

    // rings: h_g history, depth 32; row padded to 72 f16 (144B = 9x16B:
    // aligned b128 slices, step-varying banks). gin: per-wave input-gate
    // spill [step&15][gate][unit-in-wave], intra-wave only.
    __shared__ __align__(16) float xrow[SQ];
    __shared__ __align__(16) _Float16 ring[3][32][72];
    __shared__ __align__(16) float gin[8][16][4][16];
    __shared__ __align__(16) float ystage[32];

    for (int i = tid; i < SQ; i += 768) xrow[i] = x[b * SQ + i];
    for (int i = tid; i < 864; i += 768) ((uint4*)ring)[i] = make_uint4(0, 0, 0, 0);

    // ---- weights: MFMA B-fragments from workspace (unchanged) ----
    const int gbase = (grp == 0) ? 0 : (grp == 1) ? 8192 : 24576;
    const int KT    = (grp == 0) ? 2 : 4;
    const uint32_t* wbp = wpk + gbase;
    auto fr = [&](int j_, int kt_) {
        return *reinterpret_cast<const uint4*>(
            wbp + (((w * 4 + j_) * KT + kt_) * 64 + l) * 4);
    };
    uint4 w00 = fr(0, 0), w01 = fr(0, 1), w10 = fr(1, 0), w11 = fr(1, 1),
          w20 = fr(2, 0), w21 = fr(2, 1), w30 = fr(3, 0), w31 = fr(3, 1);
    pin4(w00); pin4(w01); pin4(w10); pin4(w11);
    pin4(w20); pin4(w21); pin4(w30); pin4(w31);
    uint4 w02 = {}, w03 = {}, w12 = {}, w13 = {},
          w22 = {}, w23 = {}, w32 = {}, w33 = {};
    if (grp != 0) {
        w02 = fr(0, 2); w03 = fr(0, 3); w12 = fr(1, 2); w13 = fr(1, 3);
        w22 = fr(2, 2); w23 = fr(2, 3); w32 = fr(3, 2); w33 = fr(3, 3);
        pin4(w02); pin4(w03); pin4(w12); pin4(w13);
        pin4(w22); pin4(w23); pin4(w32); pin4(w33);
    }
    uint4 wy2 = {}, wy3 = {};
    f32x4 cy = {0.f, 0.f, 0.f, 0.f};
    if (grp0w1) {
        wy2 = *reinterpret_cast<const uint4*>(wpk + 40960 + (0 * 64 + l) * 4);
        wy3 = *reinterpret_cast<const uint4*>(wpk + 40960 + (1 * 64 + l) * 4);
        pin4(wy2); pin4(wy3);
        const float bv = blin[0];
        cy = f32x4{bv, bv, bv, bv};
        pinv(cy);
    }

    // ---- persistent bias C-operands ----
    const float* bi = (grp == 0) ? bih0 : (grp == 1) ? bih1 : bih2;
    const float* bh = (grp == 0) ? bhh0 : (grp == 1) ? bhh1 : bhh2;
    const float bs0 = bi[unit]       + bh[unit];
    const float bs1 = bi[64 + unit]  + bh[64 + unit];
    const float bs2 = bi[128 + unit] + bh[128 + unit];
    const float bs3 = bi[192 + unit] + bh[192 + unit];
    f32x4 cb0 = {bs0, bs0, bs0, bs0};  pinv(cb0);
    f32x4 cb1 = {bs1, bs1, bs1, bs1};  pinv(cb1);
    f32x4 cb2 = {bs2, bs2, bs2, bs2};  pinv(cb2);
    f32x4 cb3 = {bs3, bs3, bs3, bs3};  pinv(cb3);

    float wx0 = 0.f, wx1 = 0.f, wx2 = 0.f, wx3 = 0.f;
    if (grp == 0) {
        wx0 = Wih0[unit];       wx1 = Wih0[64 + unit];
        wx2 = Wih0[128 + unit]; wx3 = Wih0[192 + unit];
    }

    const f32x4 Z = {0.f, 0.f, 0.f, 0.f};
    float cc = 0.f;
    const int skew = (grp == 1) ? SK1 : SK2;

    __syncthreads();

    for (int T = 0; T < SQ + SKH; ++T) {
        if (grp == 0) {
            // ---- l0: self matvec on h0(T-1) (8 MFMAs) ----
            const _Float16* sp = &ring[0][(T + 31) & 31][0];
            const uint4 a0 = *(const uint4*)(sp + q * 8);
            const uint4 a1 = *(const uint4*)(sp + 32 + q * 8);
            f32x4 d0 = mm(a0, w00, cb0); d0 = mm(a1, w01, d0);
            f32x4 d1 = mm(a0, w10, cb1); d1 = mm(a1, w11, d1);
            f32x4 d2 = mm(a0, w20, cb2); d2 = mm(a1, w21, d2);
            f32x4 d3 = mm(a0, w30, cb3); d3 = mm(a1, w31, d3);

            if (grp0w1) {
                // head: y(T-38) from the h2 ring (l2 wrote that row at T-2)
                const int sy = T - SKH;
                if (sy >= 0) {
                    const _Float16* hp = &ring[2][sy & 31][0];
                    const uint4 y0 = *(const uint4*)(hp + q * 8);
                    const uint4 y1 = *(const uint4*)(hp + 32 + q * 8);
                    f32x4 d4 = mm(y0, wy2, cy);
                    d4 = mm(y1, wy3, d4);
                    if (l == 0) ystage[sy & 31] = d4[0];
                    if ((sy & 31) == 31) {
                        const float yv = ystage[l & 31];
                        if (l < 32) out[b * SQ + (sy - 31) + l] = yv;
                    }
                }
            }

            if (T < SQ) {
                const float xT = xrow[T];
                float gi = d0[0] + wx0 * xT;
                float gf = d1[0] + wx1 * xT;
                float gg = d2[0] + wx2 * xT;
                float go = d3[0] + wx3 * xT;
                const float i_ = frcp(1.f + fexp2(gi * -1.44269504f));
                const float f_ = frcp(1.f + fexp2(gf * -1.44269504f));
                const float o_ = frcp(1.f + fexp2(go * -1.44269504f));
                const float tg = 2.f * frcp(1.f + fexp2(gg * -2.88539008f)) - 1.f;
                cc = f_ * cc + i_ * tg;
                const float tc = fminf(fmaxf(cc, -15.f), 15.f);
                const float e  = fexp2(tc * -2.88539008f);
                const float h  = o_ * ((1.f - e) * frcp(1.f + e));
                if (l < 16) {
                    ring[0][T & 31][unit] = (_Float16)h;
                    if (T == SQ - 1) {
                        out[NB * SQ + b * HH + unit] = h;
                        out[NB * SQ + 3 * NB * HH + b * HH + unit] = cc;
                    }
                }
            }
        } else {
            const int s = T - skew;
            if (s >= 0) {
                // ---- input-side batch: 16 steps per 8 MFMAs, A rows=steps.
                // h_in rows s..s+15 are 3..18 barriers old (safe; distinct
                // mod 32 from the producer's current write row).
                if ((s & 15) == 0 && s < SQ) {
                    const _Float16* bp = &ring[grp - 1][(s + n) & 31][q * 8];
                    const uint4 ab0 = *(const uint4*)bp;
                    const uint4 ab1 = *(const uint4*)(bp + 32);
                    f32x4 e0 = mm(ab0, w00, Z); e0 = mm(ab1, w01, e0);
                    f32x4 e1 = mm(ab0, w10, Z); e1 = mm(ab1, w11, e1);
                    f32x4 e2 = mm(ab0, w20, Z); e2 = mm(ab1, w21, e2);
                    f32x4 e3 = mm(ab0, w30, Z); e3 = mm(ab1, w31, e3);
                    // spill D (row = step offset (l>>4)*4+jj, col = unit n)
#pragma unroll
                    for (int jj = 0; jj < 4; ++jj) {
                        gin[wg][q * 4 + jj][0][n] = e0[jj];
                        gin[wg][q * 4 + jj][1][n] = e1[jj];
                        gin[wg][q * 4 + jj][2][n] = e2[jj];
                        gin[wg][q * 4 + jj][3][n] = e3[jj];
                    }
                }

                // ---- self matvec on own h(s-1) (8 MFMAs, bias in C) ----
                const _Float16* sp = &ring[grp][(s + 31) & 31][0];
                const uint4 c0 = *(const uint4*)(sp + q * 8);
                const uint4 c1 = *(const uint4*)(sp + 32 + q * 8);
                f32x4 d0 = mm(c0, w02, cb0); d0 = mm(c1, w03, d0);
                f32x4 d1 = mm(c0, w12, cb1); d1 = mm(c1, w13, d1);
                f32x4 d2 = mm(c0, w22, cb2); d2 = mm(c1, w23, d2);
                f32x4 d3 = mm(c0, w32, cb3); d3 = mm(c1, w33, d3);

                if (s < SQ) {
                    const int r = s & 15;
                    float gi = d0[0] + gin[wg][r][0][n];
                    float gf = d1[0] + gin[wg][r][1][n];
                    float gg = d2[0] + gin[wg][r][2][n];
                    float go = d3[0] + gin[wg][r][3][n];
                    const float i_ = frcp(1.f + fexp2(gi * -1.44269504f));
                    const float f_ = frcp(1.f + fexp2(gf * -1.44269504f));
                    const float o_ = frcp(1.f + fexp2(go * -1.44269504f));
                    const float tg = 2.f * frcp(1.f + fexp2(gg * -2.88539008f)) - 1.f;
                    cc = f_ * cc + i_ * tg;
                    const float tc = fminf(fmaxf(cc, -15.f), 15.f);
                    const float e  = fexp2(tc * -2.88539008f);
                    const float h  = o_ * ((1.f - e) * frcp(1.f + e));
                    if (l < 16) {
                        ring[grp][s & 31][unit] = (_Float16)h;
                        if (s == SQ - 1) {
                            out[NB * SQ + grp * NB * HH + b * HH + unit] = h;
                            out[NB * SQ + 3 * NB * HH + grp * NB * HH + b * HH + unit] = cc;
                        }
                    }
                }
            }
        }
        __syncthreads();
    }
}

extern "C" void kernel_launch(void* const* d_in, const int* in_sizes, int n_in,
                              void* d_out, int out_size, void* d_ws, size_t ws_size,
                              hipStream_t stream) {
    const float* x    = (const float*)d_in[0];
    const float* Wih0 = (const float*)d_in[1];
    const float* Whh0 = (const float*)d_in[2];
    const float* bih0 = (const float*)d_in[3];
    const float* bhh0 = (const float*)d_in[4];
    const float* Wih1 = (const float*)d_in[5];
    const float* Whh1 = (const float*)d_in[6];
    const float* bih1 = (const float*)d_in[7];
    const float* bhh1 = (const float*)d_in[8];
    const float* Wih2 = (const float*)d_in[9];
    const float* Whh2 = (const float*)d_in[10];
    const float* bih2 = (const float*)d_in[11];
    const float* bhh2 = (const float*)d_in[12];
    const float* Wlin = (const float*)d_in[13];
    const float* blin = (const float*)d_in[14];
    float* out = (float*)d_out;

    uint32_t* wpk = (uint32_t*)d_ws;   // 41472 u32 = 162 KiB < ws_size
    prep_weights<<<162, 256, 0, stream>>>(Whh0, Wih1, Whh1, Wih2, Whh2, Wlin, wpk);
    lstm3_fused<<<NB, 768, 0, stream>>>(x, Wih0, bih0, bhh0,
                                        bih1, bhh1, bih2, bhh2,
                                        blin, wpk, out);
}